// Round 8
// baseline (282.290 us; speedup 1.0000x reference)
//
#include <hip/hip_runtime.h>
#include <hip/hip_bf16.h>

typedef unsigned short u16;
typedef __bf16 bf16x8 __attribute__((ext_vector_type(8)));
typedef float floatx4 __attribute__((ext_vector_type(4)));

#define B_ 4
#define N_ 2048
#define C_ 1024
#define H_ 16
#define HD_ 64

__device__ __forceinline__ float b2f(u16 u) {
    union { float f; unsigned int i; } v; v.i = ((unsigned int)u) << 16; return v.f;
}
__device__ __forceinline__ u16 f2b(float f) {
    union { float f; unsigned int i; } v; v.f = f;
    unsigned int i = v.i;
    unsigned int r = i + 0x7FFFu + ((i >> 16) & 1u);
    return (u16)(r >> 16);
}
__device__ __forceinline__ unsigned int pk2(float a, float b) {
    __hip_bfloat162 t = __float22bfloat162_rn(float2{a, b});
    unsigned int u; __builtin_memcpy(&u, &t, 4); return u;
}
// async global->LDS, 16B per lane; LDS dest = wave-uniform base + lane*16
__device__ __forceinline__ void async16(const u16* g, u16* l) {
    __builtin_amdgcn_global_load_lds((const __attribute__((address_space(1))) unsigned int*)g,
                                     (__attribute__((address_space(3))) unsigned int*)l,
                                     16, 0, 0);
}

// ---------------------------------------------------------------------------
// Kernel 1: x = inputs(fp32) + sinusoidal PE  ->  bf16 x.
// ---------------------------------------------------------------------------
__global__ __launch_bounds__(256) void pe_add_kernel(const float* __restrict__ in,
                                                     u16* __restrict__ x) {
    int idx = blockIdx.x * 256 + threadIdx.x;      // pair index, total B*N*C/2
    int cp  = idx & 511;                            // C/2 = 512 pairs per row
    int row = idx >> 9;                             // b*N + n
    int n   = row & (N_ - 1);
    float r = exp2f(-13.287712379549449f * ((float)cp * (1.0f / 512.0f)));
    float ang = (float)n * r;
    float s, c;
    sincosf(ang, &s, &c);
    float2 pr = ((const float2*)in)[idx];
    unsigned int o = ((unsigned int)f2b(pr.y + c) << 16) | (unsigned int)f2b(pr.x + s);
    ((unsigned int*)x)[idx] = o;
}

// ---------------------------------------------------------------------------
// Kernel 2: transpose W_qkv fp32 [1024][3072] -> bf16 Wt [3072][1024].
// ---------------------------------------------------------------------------
__global__ __launch_bounds__(256) void wt_kernel(const float* __restrict__ W,
                                                 u16* __restrict__ Wt) {
    __shared__ u16 tile[32][33];
    int bx = blockIdx.x;            // over 3072/32 = 96
    int by = blockIdx.y;            // over 1024/32 = 32
    int tx = threadIdx.x & 31;
    int ty = threadIdx.x >> 5;      // 0..7
    for (int i = 0; i < 32; i += 8)
        tile[ty + i][tx] = f2b(W[(size_t)(by * 32 + ty + i) * 3072 + bx * 32 + tx]);
    __syncthreads();
    for (int i = 0; i < 32; i += 8)
        Wt[(size_t)(bx * 32 + ty + i) * 1024 + by * 32 + tx] = tile[tx][ty + i];
}

// ---------------------------------------------------------------------------
// Kernel 3: QKV GEMM, BK=64 (unchanged, proven).
// ---------------------------------------------------------------------------
__global__ __launch_bounds__(256) void qkv_gemm_kernel(const u16* __restrict__ X,
                                                       const u16* __restrict__ Wt,
                                                       u16* __restrict__ q,
                                                       u16* __restrict__ k,
                                                       u16* __restrict__ vt) {
    __shared__ u16 As[128 * 64];
    __shared__ u16 Bs[128 * 64];
    int tid  = threadIdx.x;
    int wave = tid >> 6, lane = tid & 63, l15 = lane & 15, quad = lane >> 4;
    int m0 = blockIdx.x * 128;
    int n0 = blockIdx.y * 128;
    int wm = (wave & 1) * 64;
    int wn = (wave >> 1) * 64;

    floatx4 acc[4][4];
    for (int i = 0; i < 4; i++)
        for (int j = 0; j < 4; j++)
            acc[i][j] = floatx4{0.f, 0.f, 0.f, 0.f};

    // staging: wave stages rows [wave*32, wave*32+32), 4 instrs of 8 rows each.
    // LDS[r][c'] = global[r][c' ^ (r&7)]  (c' = lane&7, r&7 = lane>>3)
    int rowOff = wave * 32 + (lane >> 3);
    int colSw  = ((lane & 7) ^ (lane >> 3)) * 8;
    const u16* gA = X  + (size_t)(m0 + rowOff) * 1024 + colSw;
    const u16* gB = Wt + (size_t)(n0 + rowOff) * 1024 + colSw;
    u16* lA = As + wave * 2048;                    // 32 rows * 64 elems
    u16* lB = Bs + wave * 2048;

    // loop-invariant frag read offsets: chunk g=kh*4+quad stored at g^(l15&7)
    int swl = l15 & 7;
    int aB0 = (wm + l15) * 64 + ((quad ^ swl) * 8);
    int aB1 = (wm + l15) * 64 + (((4 + quad) ^ swl) * 8);
    int bB0 = (wn + l15) * 64 + ((quad ^ swl) * 8);
    int bB1 = (wn + l15) * 64 + (((4 + quad) ^ swl) * 8);

    for (int k0 = 0; k0 < 1024; k0 += 64) {
        __syncthreads();                            // prev tile consumed
        async16(gA + k0,             lA);
        async16(gA + k0 +  8 * 1024, lA + 512);
        async16(gA + k0 + 16 * 1024, lA + 1024);
        async16(gA + k0 + 24 * 1024, lA + 1536);
        async16(gB + k0,             lB);
        async16(gB + k0 +  8 * 1024, lB + 512);
        async16(gB + k0 + 16 * 1024, lB + 1024);
        async16(gB + k0 + 24 * 1024, lB + 1536);
        __syncthreads();                            // vmcnt(0) drain + barrier

        bf16x8 af[4][2], bf[4][2];
        for (int i = 0; i < 4; i++) {
            af[i][0] = *(const bf16x8*)(As + aB0 + i * 16 * 64);
            af[i][1] = *(const bf16x8*)(As + aB1 + i * 16 * 64);
        }
        for (int j = 0; j < 4; j++) {
            bf[j][0] = *(const bf16x8*)(Bs + bB0 + j * 16 * 64);
            bf[j][1] = *(const bf16x8*)(Bs + bB1 + j * 16 * 64);
        }
        for (int i = 0; i < 4; i++)
            for (int j = 0; j < 4; j++) {
                acc[i][j] = __builtin_amdgcn_mfma_f32_16x16x32_bf16(af[i][0], bf[j][0], acc[i][j], 0, 0, 0);
                acc[i][j] = __builtin_amdgcn_mfma_f32_16x16x32_bf16(af[i][1], bf[j][1], acc[i][j], 0, 0, 0);
            }
    }

    // epilogue: C[m][n], m = m0+wm+i*16+quad*4+r, n_col = n0+wn+j*16+l15
    const float QSC = 0.125f * 1.44269504f;        // folded scale*log2e for q
    for (int i = 0; i < 4; i++) {
        int gm   = m0 + wm + i * 16 + quad * 4;
        int b    = gm >> 11;                       // / 2048
        int nloc = gm & 2047;
        for (int j = 0; j < 4; j++) {
            int gn    = n0 + wn + j * 16 + l15;
            int which = gn >> 10;                  // 0=q 1=k 2=v (wave-uniform)
            int cc    = gn & 1023;
            int h     = cc >> 6;
            int d     = cc & 63;
            size_t bh = (size_t)(b * 16 + h);
            if (which == 2) {
                ushort4 w4;
                w4.x = f2b(acc[i][j][0]);
                w4.y = f2b(acc[i][j][1]);
                w4.z = f2b(acc[i][j][2]);
                w4.w = f2b(acc[i][j][3]);
                *(ushort4*)(vt + (bh * 64 + d) * 2048 + nloc) = w4;  // 4 consecutive n
            } else {
                u16* dst = (which == 0) ? q : k;
                float sc = (which == 0) ? QSC : 1.0f;
                for (int r = 0; r < 4; r++)
                    dst[(bh * 2048 + nloc + r) * 64 + d] = f2b(acc[i][j][r] * sc);
            }
        }
    }
}

// ---------------------------------------------------------------------------
// Kernel 4: flash attention — R9: counted-vmcnt depth-2 pipeline (T4) +
// XCD-clustered 1D grid (T1) + setprio (T5).
// R8 post-mortem: compiler's vmcnt(0)-before-__syncthreads drains the 1-deep
// prefetch every tile -> latency-bound (VALU 61 / Mfma 21 / Occ 34).
// Fix: ring-4 K/V buffers; per tile each wave issues exactly 2 async16 for
// tile i+2; barrier = asm s_waitcnt vmcnt(2) + raw s_barrier + sched_barrier
// -> tile i+1's loads stay in flight ACROSS the barrier (2 compute phases to
// land, covers HBM miss).  Mask row staged to LDS once (8 KB) so the loop
// has ZERO stray VMEM ops and vmcnt arithmetic is exact.
// Grid: 1D 1024, bh = bid&63 -> dispatch id % 8 == bh % 8: all 16 q-blocks
// of a (b,h) on one XCD -> K/V L2-resident per XCD.
// LDS: K 4x4KB + V 4x4KB + P 10KB + mask 8KB = 50KB -> 3 blocks/CU.
// Race audit: stage at body i targets buf (i+2)%4, last read tile i-2 whose
// reads completed before barrier(i-1); vmcnt FIFO -> vmcnt(2) completes the
// oldest 2 (tile i); tail clamps stage addr (dead-buffer restage, harmless).
// ---------------------------------------------------------------------------
__global__ __launch_bounds__(256, 3) void attn_kernel(const u16* __restrict__ q,
                                                      const u16* __restrict__ k,
                                                      const u16* __restrict__ vt,
                                                      const float* __restrict__ mask,
                                                      float* __restrict__ out) {
    __shared__ u16 Ks[4][32 * 64];    // [key][d]  linear, source-swizzled
    __shared__ u16 Vs[4][64 * 32];    // [d][key]  linear, source-swizzled
    __shared__ u16 Ps[4][32 * 40];    // per-wave [q][key], stride 40
    __shared__ __align__(16) float Ms[2048];   // mask row of this b

    int tid  = threadIdx.x;
    int wave = tid >> 6, lane = tid & 63, l15 = lane & 15, quad = lane >> 4;
    int bid = blockIdx.x;             // 1D: bh fastest -> XCD = bh%8 cluster
    int bh = bid & 63, qb = bid >> 6;
    int b = bh >> 4, h = bh & 15;
    size_t base = (size_t)bh * (N_ * 64);
    int q0 = qb * 128 + wave * 32;
    const float* mkb = mask + b * N_;

    // stage mask row into LDS (256 thr x 8 floats)
    {
        float4 m0 = *(const float4*)(mkb + tid * 8);
        float4 m1 = *(const float4*)(mkb + tid * 8 + 4);
        *(float4*)(Ms + tid * 8)     = m0;
        *(float4*)(Ms + tid * 8 + 4) = m1;
    }

    // Q as B-operand fragments (q pre-scaled by 0.125*log2e at GEMM time)
    bf16x8 qf[2][2];
#pragma unroll
    for (int s = 0; s < 2; s++)
#pragma unroll
        for (int dc = 0; dc < 2; dc++)
            qf[s][dc] = *(const bf16x8*)(q + base + (size_t)(q0 + s * 16 + l15) * 64 + dc * 32 + quad * 8);

    const float L2E = 1.44269504f;
    float nmq[2];
    nmq[0] = -L2E * mkb[q0 + l15];
    nmq[1] = -L2E * mkb[q0 + 16 + l15];

    floatx4 acc[2][4];                // [s][dt]
#pragma unroll
    for (int s = 0; s < 2; s++)
#pragma unroll
        for (int dt = 0; dt < 4; dt++)
            acc[s][dt] = floatx4{0.f, 0.f, 0.f, 0.f};
    float lp[2] = {0.f, 0.f};

    // async16 staging, 1 K-instr + 1 V-instr per wave per tile:
    //   K instr: 8 rows x 8 chunks;  wave w covers K rows [w*8,  w*8+8)
    //   V instr: 16 rows x 4 chunks; wave w covers V rows [w*16, w*16+16)
    int krow = wave * 8  + (lane >> 3);
    int kcol = ((lane & 7) ^ (lane >> 3)) * 8;            // chunk ^ (r&7)
    int vrow = wave * 16 + (lane >> 2);
    int vcol = ((lane & 3) ^ ((lane >> 2) & 3)) * 8;      // chunk ^ (r&3)
    const u16* gK = k  + base + (size_t)krow * 64 + kcol;            // += kt*64
    const u16* gV = vt + ((size_t)bh * 64 + vrow) * 2048 + vcol;     // += kt
    int wof = wave * 512;             // wave-uniform LDS stage offset

    // loop-invariant swizzled frag-read offsets
    int a0 = ((quad    ) ^ (l15 & 7)) * 8;    // K chunks 0..7  -> d = quad*8
    int a1 = ((4 + quad) ^ (l15 & 7)) * 8;    //                -> d = 32+quad*8
    int av = ( quad      ^ (l15 & 3)) * 8;    // V chunks 0..3  -> key = quad*8

    u16* Pw = Ps[wave];

    // one KVBLK=32 tile body; barrier+counted-vmcnt at TOP.
    auto TILE = [&](int kt, const u16* Kb, const u16* Vb, u16* Kn, u16* Vn) {
        asm volatile("s_waitcnt vmcnt(2)" ::: "memory");
        __builtin_amdgcn_s_barrier();
        __builtin_amdgcn_sched_barrier(0);
        int nkt = kt + 64; if (nkt > N_ - 32) nkt = N_ - 32;   // clamp (dead restage)
        async16(gK + (size_t)nkt * 64, Kn);
        async16(gV + nkt,              Vn);
        float4 mkv0 = *(const float4*)(Ms + kt + quad * 4);
        float4 mkv1 = *(const float4*)(Ms + kt + 16 + quad * 4);
        // S^T (key x q) + softmax; q pre-scaled, no max subtraction
#pragma unroll
        for (int t = 0; t < 2; t++) {
            bf16x8 kf0 = *(const bf16x8*)(Kb + (t * 16 + l15) * 64 + a0);
            bf16x8 kf1 = *(const bf16x8*)(Kb + (t * 16 + l15) * 64 + a1);
            float4 mk = t ? mkv1 : mkv0;
#pragma unroll
            for (int s = 0; s < 2; s++) {
                floatx4 sa = floatx4{0.f, 0.f, 0.f, 0.f};
                __builtin_amdgcn_s_setprio(1);
                sa = __builtin_amdgcn_mfma_f32_16x16x32_bf16(kf0, qf[s][0], sa, 0, 0, 0);
                sa = __builtin_amdgcn_mfma_f32_16x16x32_bf16(kf1, qf[s][1], sa, 0, 0, 0);
                __builtin_amdgcn_s_setprio(0);
                float p0 = exp2f(fmaf(nmq[s], mk.x, sa[0]));
                float p1 = exp2f(fmaf(nmq[s], mk.y, sa[1]));
                float p2 = exp2f(fmaf(nmq[s], mk.z, sa[2]));
                float p3 = exp2f(fmaf(nmq[s], mk.w, sa[3]));
                lp[s] += (p0 + p1) + (p2 + p3);
                uint2 w; w.x = pk2(p0, p1); w.y = pk2(p2, p3);
                *(uint2*)(Pw + (s * 16 + l15) * 40 + t * 16 + quad * 4) = w;
            }
        }
        // PV: K-dim = 32 keys = single MFMA per (s,dt)
        bf16x8 pf0 = *(const bf16x8*)(Pw + l15 * 40 + quad * 8);
        bf16x8 pf1 = *(const bf16x8*)(Pw + (16 + l15) * 40 + quad * 8);
#pragma unroll
        for (int dt = 0; dt < 4; dt++) {
            bf16x8 vf = *(const bf16x8*)(Vb + (dt * 16 + l15) * 32 + av);
            __builtin_amdgcn_s_setprio(1);
            acc[0][dt] = __builtin_amdgcn_mfma_f32_16x16x32_bf16(pf0, vf, acc[0][dt], 0, 0, 0);
            acc[1][dt] = __builtin_amdgcn_mfma_f32_16x16x32_bf16(pf1, vf, acc[1][dt], 0, 0, 0);
            __builtin_amdgcn_s_setprio(0);
        }
    };

    // prologue: stage tiles 0,1; full drain once (fills tile-0 data).
    async16(gK,           Ks[0] + wof);
    async16(gV,           Vs[0] + wof);
    async16(gK + 32 * 64, Ks[1] + wof);
    async16(gV + 32,      Vs[1] + wof);
    __syncthreads();

    for (int m = 0; m < 16; ++m) {
        int kt = m * 128;
        TILE(kt,      Ks[0], Vs[0], Ks[2] + wof, Vs[2] + wof);
        TILE(kt + 32, Ks[1], Vs[1], Ks[3] + wof, Vs[3] + wof);
        TILE(kt + 64, Ks[2], Vs[2], Ks[0] + wof, Vs[0] + wof);
        TILE(kt + 96, Ks[3], Vs[3], Ks[1] + wof, Vs[1] + wof);
    }

    // l reduction (once) + epilogue.  acc C-layout: col=l15=d, row=quad*4+r=q
#pragma unroll
    for (int s = 0; s < 2; s++) {
        float lf = lp[s];
        lf += __shfl_xor(lf, 16);
        lf += __shfl_xor(lf, 32);
        float invl = 1.0f / lf;                // lane l15 holds inv-l of q=s*16+l15
#pragma unroll
        for (int r = 0; r < 4; r++) {
            float ir = __shfl(invl, (lane & 48) | (quad * 4 + r));
            int qrow = q0 + s * 16 + quad * 4 + r;
            float* orow = out + ((size_t)(b * N_ + qrow)) * C_ + h * 64;
#pragma unroll
            for (int dt = 0; dt < 4; dt++)
                orow[dt * 16 + l15] = acc[s][dt][r] * ir;
        }
    }
}

// ---------------------------------------------------------------------------
extern "C" void kernel_launch(void* const* d_in, const int* in_sizes, int n_in,
                              void* d_out, int out_size, void* d_ws, size_t ws_size,
                              hipStream_t stream) {
    const float* inp  = (const float*)d_in[0];   // inputs  [B,N,C] fp32
    const float* mask = (const float*)d_in[1];   // mask    [B,N]   fp32
    const float* W    = (const float*)d_in[2];   // W_qkv   [C,3C]  fp32
    float* out = (float*)d_out;                  // [B,N,C] fp32

    char* ws = (char*)d_ws;
    u16* x  = (u16*)ws;                              // 16 MB  x=in+PE bf16
    u16* Wt = (u16*)(ws + 16777216);                 // 6 MB   W^T bf16
    u16* q  = (u16*)(ws + 23068672);                 // [B,H,N,64] bf16 (pre-scaled)
    u16* k  = q + 8388608;
    u16* vt = k + 8388608;                           // [B,H,64,N] bf16 (v transposed)

    pe_add_kernel<<<16384, 256, 0, stream>>>(inp, x);
    wt_kernel<<<dim3(96, 32), 256, 0, stream>>>(W, Wt);
    qkv_gemm_kernel<<<dim3(64, 24), 256, 0, stream>>>(x, Wt, q, k, vt);
    attn_kernel<<<1024, 256, 0, stream>>>(q, k, vt, mask, out);
}

// Round 9
// 280.555 us; speedup vs baseline: 1.0062x; 1.0062x over previous
//
#include <hip/hip_runtime.h>
#include <hip/hip_bf16.h>

typedef unsigned short u16;
typedef __bf16 bf16x8 __attribute__((ext_vector_type(8)));
typedef float floatx4 __attribute__((ext_vector_type(4)));

#define B_ 4
#define N_ 2048
#define C_ 1024
#define H_ 16
#define HD_ 64

__device__ __forceinline__ float b2f(u16 u) {
    union { float f; unsigned int i; } v; v.i = ((unsigned int)u) << 16; return v.f;
}
__device__ __forceinline__ u16 f2b(float f) {
    union { float f; unsigned int i; } v; v.f = f;
    unsigned int i = v.i;
    unsigned int r = i + 0x7FFFu + ((i >> 16) & 1u);
    return (u16)(r >> 16);
}
__device__ __forceinline__ unsigned int pk2(float a, float b) {
    __hip_bfloat162 t = __float22bfloat162_rn(float2{a, b});
    unsigned int u; __builtin_memcpy(&u, &t, 4); return u;
}
// async global->LDS, 16B per lane; LDS dest = wave-uniform base + lane*16
__device__ __forceinline__ void async16(const u16* g, u16* l) {
    __builtin_amdgcn_global_load_lds((const __attribute__((address_space(1))) unsigned int*)g,
                                     (__attribute__((address_space(3))) unsigned int*)l,
                                     16, 0, 0);
}

// ---------------------------------------------------------------------------
// Kernel 1: x = inputs(fp32) + sinusoidal PE  ->  bf16 x.
// ---------------------------------------------------------------------------
__global__ __launch_bounds__(256) void pe_add_kernel(const float* __restrict__ in,
                                                     u16* __restrict__ x) {
    int idx = blockIdx.x * 256 + threadIdx.x;      // pair index, total B*N*C/2
    int cp  = idx & 511;                            // C/2 = 512 pairs per row
    int row = idx >> 9;                             // b*N + n
    int n   = row & (N_ - 1);
    float r = exp2f(-13.287712379549449f * ((float)cp * (1.0f / 512.0f)));
    float ang = (float)n * r;
    float s, c;
    sincosf(ang, &s, &c);
    float2 pr = ((const float2*)in)[idx];
    unsigned int o = ((unsigned int)f2b(pr.y + c) << 16) | (unsigned int)f2b(pr.x + s);
    ((unsigned int*)x)[idx] = o;
}

// ---------------------------------------------------------------------------
// Kernel 2: transpose W_qkv fp32 [1024][3072] -> bf16 Wt [3072][1024].
// ---------------------------------------------------------------------------
__global__ __launch_bounds__(256) void wt_kernel(const float* __restrict__ W,
                                                 u16* __restrict__ Wt) {
    __shared__ u16 tile[32][33];
    int bx = blockIdx.x;            // over 3072/32 = 96
    int by = blockIdx.y;            // over 1024/32 = 32
    int tx = threadIdx.x & 31;
    int ty = threadIdx.x >> 5;      // 0..7
    for (int i = 0; i < 32; i += 8)
        tile[ty + i][tx] = f2b(W[(size_t)(by * 32 + ty + i) * 3072 + bx * 32 + tx]);
    __syncthreads();
    for (int i = 0; i < 32; i += 8)
        Wt[(size_t)(bx * 32 + ty + i) * 1024 + by * 32 + tx] = tile[tx][ty + i];
}

// ---------------------------------------------------------------------------
// Kernel 3: QKV GEMM, BK=64 (unchanged, proven).
// ---------------------------------------------------------------------------
__global__ __launch_bounds__(256) void qkv_gemm_kernel(const u16* __restrict__ X,
                                                       const u16* __restrict__ Wt,
                                                       u16* __restrict__ q,
                                                       u16* __restrict__ k,
                                                       u16* __restrict__ vt) {
    __shared__ u16 As[128 * 64];
    __shared__ u16 Bs[128 * 64];
    int tid  = threadIdx.x;
    int wave = tid >> 6, lane = tid & 63, l15 = lane & 15, quad = lane >> 4;
    int m0 = blockIdx.x * 128;
    int n0 = blockIdx.y * 128;
    int wm = (wave & 1) * 64;
    int wn = (wave >> 1) * 64;

    floatx4 acc[4][4];
    for (int i = 0; i < 4; i++)
        for (int j = 0; j < 4; j++)
            acc[i][j] = floatx4{0.f, 0.f, 0.f, 0.f};

    // staging: wave stages rows [wave*32, wave*32+32), 4 instrs of 8 rows each.
    // LDS[r][c'] = global[r][c' ^ (r&7)]  (c' = lane&7, r&7 = lane>>3)
    int rowOff = wave * 32 + (lane >> 3);
    int colSw  = ((lane & 7) ^ (lane >> 3)) * 8;
    const u16* gA = X  + (size_t)(m0 + rowOff) * 1024 + colSw;
    const u16* gB = Wt + (size_t)(n0 + rowOff) * 1024 + colSw;
    u16* lA = As + wave * 2048;                    // 32 rows * 64 elems
    u16* lB = Bs + wave * 2048;

    // loop-invariant frag read offsets: chunk g=kh*4+quad stored at g^(l15&7)
    int swl = l15 & 7;
    int aB0 = (wm + l15) * 64 + ((quad ^ swl) * 8);
    int aB1 = (wm + l15) * 64 + (((4 + quad) ^ swl) * 8);
    int bB0 = (wn + l15) * 64 + ((quad ^ swl) * 8);
    int bB1 = (wn + l15) * 64 + (((4 + quad) ^ swl) * 8);

    for (int k0 = 0; k0 < 1024; k0 += 64) {
        __syncthreads();                            // prev tile consumed
        async16(gA + k0,             lA);
        async16(gA + k0 +  8 * 1024, lA + 512);
        async16(gA + k0 + 16 * 1024, lA + 1024);
        async16(gA + k0 + 24 * 1024, lA + 1536);
        async16(gB + k0,             lB);
        async16(gB + k0 +  8 * 1024, lB + 512);
        async16(gB + k0 + 16 * 1024, lB + 1024);
        async16(gB + k0 + 24 * 1024, lB + 1536);
        __syncthreads();                            // vmcnt(0) drain + barrier

        bf16x8 af[4][2], bf[4][2];
        for (int i = 0; i < 4; i++) {
            af[i][0] = *(const bf16x8*)(As + aB0 + i * 16 * 64);
            af[i][1] = *(const bf16x8*)(As + aB1 + i * 16 * 64);
        }
        for (int j = 0; j < 4; j++) {
            bf[j][0] = *(const bf16x8*)(Bs + bB0 + j * 16 * 64);
            bf[j][1] = *(const bf16x8*)(Bs + bB1 + j * 16 * 64);
        }
        for (int i = 0; i < 4; i++)
            for (int j = 0; j < 4; j++) {
                acc[i][j] = __builtin_amdgcn_mfma_f32_16x16x32_bf16(af[i][0], bf[j][0], acc[i][j], 0, 0, 0);
                acc[i][j] = __builtin_amdgcn_mfma_f32_16x16x32_bf16(af[i][1], bf[j][1], acc[i][j], 0, 0, 0);
            }
    }

    // epilogue: C[m][n], m = m0+wm+i*16+quad*4+r, n_col = n0+wn+j*16+l15
    const float QSC = 0.125f * 1.44269504f;        // folded scale*log2e for q
    for (int i = 0; i < 4; i++) {
        int gm   = m0 + wm + i * 16 + quad * 4;
        int b    = gm >> 11;                       // / 2048
        int nloc = gm & 2047;
        for (int j = 0; j < 4; j++) {
            int gn    = n0 + wn + j * 16 + l15;
            int which = gn >> 10;                  // 0=q 1=k 2=v (wave-uniform)
            int cc    = gn & 1023;
            int h     = cc >> 6;
            int d     = cc & 63;
            size_t bh = (size_t)(b * 16 + h);
            if (which == 2) {
                ushort4 w4;
                w4.x = f2b(acc[i][j][0]);
                w4.y = f2b(acc[i][j][1]);
                w4.z = f2b(acc[i][j][2]);
                w4.w = f2b(acc[i][j][3]);
                *(ushort4*)(vt + (bh * 64 + d) * 2048 + nloc) = w4;  // 4 consecutive n
            } else {
                u16* dst = (which == 0) ? q : k;
                float sc = (which == 0) ? QSC : 1.0f;
                for (int r = 0; r < 4; r++)
                    dst[(bh * 2048 + nloc + r) * 64 + d] = f2b(acc[i][j][r] * sc);
            }
        }
    }
}

// ---------------------------------------------------------------------------
// Kernel 4: flash attention — R10: VALU diet on the R9 structure.
// R9 post-mortem: 3 schedules all ~145 us; VALU issue ~100 instr/wave-tile is
// the pole (204K of 357K cyc), not the staging schedule.  Cuts:
//  (1) mask-product as MFMA C-init: sa[r] = nmq[s]*mk[r] seeds the QK^T
//      accumulator (replaces zero-init + post-MFMA fmaf: -16 VALU/tile).
//  (2) softmax denominator via ones-MFMA: accl[s] = mfma(pf[s], ONES, accl)
//      -> accl[s][r] = l(q=quad*4+r), same row-mapping as O accumulator:
//      epilogue ir = 1/accl[s][r], NO shuffles (-12 VALU/tile + epilogue).
//      Denominator sums bf16-rounded P = consistent with bf16-P numerator.
//  Kept from R9: XCD-clustered 1D grid (FETCH 140->42 MB, proven), ring-4
//  K/V + counted vmcnt(2) + raw barrier, setprio, mask row in LDS.
// Falsifiers: dur -<5% -> VALU not elastic (stalls structural) -> pivot to
// GEMM 8-phase next; absmax > 2^-7 -> revert (2) only.
// ---------------------------------------------------------------------------
__global__ __launch_bounds__(256, 3) void attn_kernel(const u16* __restrict__ q,
                                                      const u16* __restrict__ k,
                                                      const u16* __restrict__ vt,
                                                      const float* __restrict__ mask,
                                                      float* __restrict__ out) {
    __shared__ u16 Ks[4][32 * 64];    // [key][d]  linear, source-swizzled
    __shared__ u16 Vs[4][64 * 32];    // [d][key]  linear, source-swizzled
    __shared__ u16 Ps[4][32 * 40];    // per-wave [q][key], stride 40
    __shared__ __align__(16) float Ms[2048];   // mask row of this b

    int tid  = threadIdx.x;
    int wave = tid >> 6, lane = tid & 63, l15 = lane & 15, quad = lane >> 4;
    int bid = blockIdx.x;             // 1D: bh fastest -> XCD = bh%8 cluster
    int bh = bid & 63, qb = bid >> 6;
    int b = bh >> 4, h = bh & 15;
    size_t base = (size_t)bh * (N_ * 64);
    int q0 = qb * 128 + wave * 32;
    const float* mkb = mask + b * N_;

    // stage mask row into LDS (256 thr x 8 floats)
    {
        float4 m0 = *(const float4*)(mkb + tid * 8);
        float4 m1 = *(const float4*)(mkb + tid * 8 + 4);
        *(float4*)(Ms + tid * 8)     = m0;
        *(float4*)(Ms + tid * 8 + 4) = m1;
    }

    // Q as B-operand fragments (q pre-scaled by 0.125*log2e at GEMM time)
    bf16x8 qf[2][2];
#pragma unroll
    for (int s = 0; s < 2; s++)
#pragma unroll
        for (int dc = 0; dc < 2; dc++)
            qf[s][dc] = *(const bf16x8*)(q + base + (size_t)(q0 + s * 16 + l15) * 64 + dc * 32 + quad * 8);

    const float L2E = 1.44269504f;
    float nmq[2];
    nmq[0] = -L2E * mkb[q0 + l15];
    nmq[1] = -L2E * mkb[q0 + 16 + l15];

    // all-ones B-fragment for the denominator MFMA
    bf16x8 onef;
#pragma unroll
    for (int i = 0; i < 8; i++) onef[i] = (__bf16)1.0f;

    floatx4 acc[2][4];                // [s][dt] PV accumulator
    floatx4 accl[2];                  // [s]     row-sum accumulator (denominator)
#pragma unroll
    for (int s = 0; s < 2; s++) {
        accl[s] = floatx4{0.f, 0.f, 0.f, 0.f};
#pragma unroll
        for (int dt = 0; dt < 4; dt++)
            acc[s][dt] = floatx4{0.f, 0.f, 0.f, 0.f};
    }

    // async16 staging, 1 K-instr + 1 V-instr per wave per tile:
    //   K instr: 8 rows x 8 chunks;  wave w covers K rows [w*8,  w*8+8)
    //   V instr: 16 rows x 4 chunks; wave w covers V rows [w*16, w*16+16)
    int krow = wave * 8  + (lane >> 3);
    int kcol = ((lane & 7) ^ (lane >> 3)) * 8;            // chunk ^ (r&7)
    int vrow = wave * 16 + (lane >> 2);
    int vcol = ((lane & 3) ^ ((lane >> 2) & 3)) * 8;      // chunk ^ (r&3)
    const u16* gK = k  + base + (size_t)krow * 64 + kcol;            // += kt*64
    const u16* gV = vt + ((size_t)bh * 64 + vrow) * 2048 + vcol;     // += kt
    int wof = wave * 512;             // wave-uniform LDS stage offset

    // loop-invariant swizzled frag-read offsets
    int a0 = ((quad    ) ^ (l15 & 7)) * 8;    // K chunks 0..7  -> d = quad*8
    int a1 = ((4 + quad) ^ (l15 & 7)) * 8;    //                -> d = 32+quad*8
    int av = ( quad      ^ (l15 & 3)) * 8;    // V chunks 0..3  -> key = quad*8

    u16* Pw = Ps[wave];

    // one KVBLK=32 tile body; barrier+counted-vmcnt at TOP.
    auto TILE = [&](int kt, const u16* Kb, const u16* Vb, u16* Kn, u16* Vn) {
        asm volatile("s_waitcnt vmcnt(2)" ::: "memory");
        __builtin_amdgcn_s_barrier();
        __builtin_amdgcn_sched_barrier(0);
        int nkt = kt + 64; if (nkt > N_ - 32) nkt = N_ - 32;   // clamp (dead restage)
        async16(gK + (size_t)nkt * 64, Kn);
        async16(gV + nkt,              Vn);
        float4 mkv0 = *(const float4*)(Ms + kt + quad * 4);
        float4 mkv1 = *(const float4*)(Ms + kt + 16 + quad * 4);
        // S^T (key x q): C seeded with nmq*mk (mask add for free); p = exp2(S)
#pragma unroll
        for (int t = 0; t < 2; t++) {
            bf16x8 kf0 = *(const bf16x8*)(Kb + (t * 16 + l15) * 64 + a0);
            bf16x8 kf1 = *(const bf16x8*)(Kb + (t * 16 + l15) * 64 + a1);
            float4 mk = t ? mkv1 : mkv0;
#pragma unroll
            for (int s = 0; s < 2; s++) {
                floatx4 sa;
                sa[0] = nmq[s] * mk.x;
                sa[1] = nmq[s] * mk.y;
                sa[2] = nmq[s] * mk.z;
                sa[3] = nmq[s] * mk.w;
                __builtin_amdgcn_s_setprio(1);
                sa = __builtin_amdgcn_mfma_f32_16x16x32_bf16(kf0, qf[s][0], sa, 0, 0, 0);
                sa = __builtin_amdgcn_mfma_f32_16x16x32_bf16(kf1, qf[s][1], sa, 0, 0, 0);
                __builtin_amdgcn_s_setprio(0);
                float p0 = exp2f(sa[0]);
                float p1 = exp2f(sa[1]);
                float p2 = exp2f(sa[2]);
                float p3 = exp2f(sa[3]);
                uint2 w; w.x = pk2(p0, p1); w.y = pk2(p2, p3);
                *(uint2*)(Pw + (s * 16 + l15) * 40 + t * 16 + quad * 4) = w;
            }
        }
        // PV (+ denominator via ones-MFMA): K-dim = 32 keys = 1 MFMA each
        bf16x8 pf0 = *(const bf16x8*)(Pw + l15 * 40 + quad * 8);
        bf16x8 pf1 = *(const bf16x8*)(Pw + (16 + l15) * 40 + quad * 8);
        __builtin_amdgcn_s_setprio(1);
        accl[0] = __builtin_amdgcn_mfma_f32_16x16x32_bf16(pf0, onef, accl[0], 0, 0, 0);
        accl[1] = __builtin_amdgcn_mfma_f32_16x16x32_bf16(pf1, onef, accl[1], 0, 0, 0);
        __builtin_amdgcn_s_setprio(0);
#pragma unroll
        for (int dt = 0; dt < 4; dt++) {
            bf16x8 vf = *(const bf16x8*)(Vb + (dt * 16 + l15) * 32 + av);
            __builtin_amdgcn_s_setprio(1);
            acc[0][dt] = __builtin_amdgcn_mfma_f32_16x16x32_bf16(pf0, vf, acc[0][dt], 0, 0, 0);
            acc[1][dt] = __builtin_amdgcn_mfma_f32_16x16x32_bf16(pf1, vf, acc[1][dt], 0, 0, 0);
            __builtin_amdgcn_s_setprio(0);
        }
    };

    // prologue: stage tiles 0,1; full drain once (fills tile-0 data).
    async16(gK,           Ks[0] + wof);
    async16(gV,           Vs[0] + wof);
    async16(gK + 32 * 64, Ks[1] + wof);
    async16(gV + 32,      Vs[1] + wof);
    __syncthreads();

    for (int m = 0; m < 16; ++m) {
        int kt = m * 128;
        TILE(kt,      Ks[0], Vs[0], Ks[2] + wof, Vs[2] + wof);
        TILE(kt + 32, Ks[1], Vs[1], Ks[3] + wof, Vs[3] + wof);
        TILE(kt + 64, Ks[2], Vs[2], Ks[0] + wof, Vs[0] + wof);
        TILE(kt + 96, Ks[3], Vs[3], Ks[1] + wof, Vs[1] + wof);
    }

    // epilogue: accl[s][r] = l(q = s*16+quad*4+r) — per-lane, no shuffles.
    // acc C-layout: col=l15=d, row=quad*4+r=q (same row-map as accl).
#pragma unroll
    for (int s = 0; s < 2; s++) {
#pragma unroll
        for (int r = 0; r < 4; r++) {
            float ir = 1.0f / accl[s][r];
            int qrow = q0 + s * 16 + quad * 4 + r;
            float* orow = out + ((size_t)(b * N_ + qrow)) * C_ + h * 64;
#pragma unroll
            for (int dt = 0; dt < 4; dt++)
                orow[dt * 16 + l15] = acc[s][dt][r] * ir;
        }
    }
}

// ---------------------------------------------------------------------------
extern "C" void kernel_launch(void* const* d_in, const int* in_sizes, int n_in,
                              void* d_out, int out_size, void* d_ws, size_t ws_size,
                              hipStream_t stream) {
    const float* inp  = (const float*)d_in[0];   // inputs  [B,N,C] fp32
    const float* mask = (const float*)d_in[1];   // mask    [B,N]   fp32
    const float* W    = (const float*)d_in[2];   // W_qkv   [C,3C]  fp32
    float* out = (float*)d_out;                  // [B,N,C] fp32

    char* ws = (char*)d_ws;
    u16* x  = (u16*)ws;                              // 16 MB  x=in+PE bf16
    u16* Wt = (u16*)(ws + 16777216);                 // 6 MB   W^T bf16
    u16* q  = (u16*)(ws + 23068672);                 // [B,H,N,64] bf16 (pre-scaled)
    u16* k  = q + 8388608;
    u16* vt = k + 8388608;                           // [B,H,64,N] bf16 (v transposed)

    pe_add_kernel<<<16384, 256, 0, stream>>>(inp, x);
    wt_kernel<<<dim3(96, 32), 256, 0, stream>>>(W, Wt);
    qkv_gemm_kernel<<<dim3(64, 24), 256, 0, stream>>>(x, Wt, q, k, vt);
    attn_kernel<<<1024, 256, 0, stream>>>(q, k, vt, mask, out);
}

// Round 10
// 269.993 us; speedup vs baseline: 1.0455x; 1.0391x over previous
//
#include <hip/hip_runtime.h>
#include <hip/hip_bf16.h>

typedef unsigned short u16;
typedef __bf16 bf16x8 __attribute__((ext_vector_type(8)));
typedef float floatx4 __attribute__((ext_vector_type(4)));

#define B_ 4
#define N_ 2048
#define C_ 1024
#define H_ 16
#define HD_ 64

__device__ __forceinline__ float b2f(u16 u) {
    union { float f; unsigned int i; } v; v.i = ((unsigned int)u) << 16; return v.f;
}
__device__ __forceinline__ u16 f2b(float f) {
    union { float f; unsigned int i; } v; v.f = f;
    unsigned int i = v.i;
    unsigned int r = i + 0x7FFFu + ((i >> 16) & 1u);
    return (u16)(r >> 16);
}
__device__ __forceinline__ unsigned int pk2(float a, float b) {
    __hip_bfloat162 t = __float22bfloat162_rn(float2{a, b});
    unsigned int u; __builtin_memcpy(&u, &t, 4); return u;
}
// async global->LDS, 16B per lane; LDS dest = wave-uniform base + lane*16
__device__ __forceinline__ void async16(const u16* g, u16* l) {
    __builtin_amdgcn_global_load_lds((const __attribute__((address_space(1))) unsigned int*)g,
                                     (__attribute__((address_space(3))) unsigned int*)l,
                                     16, 0, 0);
}
__device__ __forceinline__ void async16p(const void* g, void* l) {
    __builtin_amdgcn_global_load_lds((const __attribute__((address_space(1))) unsigned int*)g,
                                     (__attribute__((address_space(3))) unsigned int*)l,
                                     16, 0, 0);
}

// ---------------------------------------------------------------------------
// Kernel 1: x = inputs(fp32) + sinusoidal PE  ->  bf16 x.
// ---------------------------------------------------------------------------
__global__ __launch_bounds__(256) void pe_add_kernel(const float* __restrict__ in,
                                                     u16* __restrict__ x) {
    int idx = blockIdx.x * 256 + threadIdx.x;      // pair index, total B*N*C/2
    int cp  = idx & 511;                            // C/2 = 512 pairs per row
    int row = idx >> 9;                             // b*N + n
    int n   = row & (N_ - 1);
    float r = exp2f(-13.287712379549449f * ((float)cp * (1.0f / 512.0f)));
    float ang = (float)n * r;
    float s, c;
    sincosf(ang, &s, &c);
    float2 pr = ((const float2*)in)[idx];
    unsigned int o = ((unsigned int)f2b(pr.y + c) << 16) | (unsigned int)f2b(pr.x + s);
    ((unsigned int*)x)[idx] = o;
}

// ---------------------------------------------------------------------------
// Kernel 2: transpose W_qkv fp32 [1024][3072] -> bf16 Wt [3072][1024].
// ---------------------------------------------------------------------------
__global__ __launch_bounds__(256) void wt_kernel(const float* __restrict__ W,
                                                 u16* __restrict__ Wt) {
    __shared__ u16 tile[32][33];
    int bx = blockIdx.x;            // over 3072/32 = 96
    int by = blockIdx.y;            // over 1024/32 = 32
    int tx = threadIdx.x & 31;
    int ty = threadIdx.x >> 5;      // 0..7
    for (int i = 0; i < 32; i += 8)
        tile[ty + i][tx] = f2b(W[(size_t)(by * 32 + ty + i) * 3072 + bx * 32 + tx]);
    __syncthreads();
    for (int i = 0; i < 32; i += 8)
        Wt[(size_t)(bx * 32 + ty + i) * 1024 + by * 32 + tx] = tile[tx][ty + i];
}

// ---------------------------------------------------------------------------
// Kernel 3: QKV GEMM, BK=64 (unchanged, proven).
// ---------------------------------------------------------------------------
__global__ __launch_bounds__(256) void qkv_gemm_kernel(const u16* __restrict__ X,
                                                       const u16* __restrict__ Wt,
                                                       u16* __restrict__ q,
                                                       u16* __restrict__ k,
                                                       u16* __restrict__ vt) {
    __shared__ u16 As[128 * 64];
    __shared__ u16 Bs[128 * 64];
    int tid  = threadIdx.x;
    int wave = tid >> 6, lane = tid & 63, l15 = lane & 15, quad = lane >> 4;
    int m0 = blockIdx.x * 128;
    int n0 = blockIdx.y * 128;
    int wm = (wave & 1) * 64;
    int wn = (wave >> 1) * 64;

    floatx4 acc[4][4];
    for (int i = 0; i < 4; i++)
        for (int j = 0; j < 4; j++)
            acc[i][j] = floatx4{0.f, 0.f, 0.f, 0.f};

    // staging: wave stages rows [wave*32, wave*32+32), 4 instrs of 8 rows each.
    // LDS[r][c'] = global[r][c' ^ (r&7)]  (c' = lane&7, r&7 = lane>>3)
    int rowOff = wave * 32 + (lane >> 3);
    int colSw  = ((lane & 7) ^ (lane >> 3)) * 8;
    const u16* gA = X  + (size_t)(m0 + rowOff) * 1024 + colSw;
    const u16* gB = Wt + (size_t)(n0 + rowOff) * 1024 + colSw;
    u16* lA = As + wave * 2048;                    // 32 rows * 64 elems
    u16* lB = Bs + wave * 2048;

    // loop-invariant frag read offsets: chunk g=kh*4+quad stored at g^(l15&7)
    int swl = l15 & 7;
    int aB0 = (wm + l15) * 64 + ((quad ^ swl) * 8);
    int aB1 = (wm + l15) * 64 + (((4 + quad) ^ swl) * 8);
    int bB0 = (wn + l15) * 64 + ((quad ^ swl) * 8);
    int bB1 = (wn + l15) * 64 + (((4 + quad) ^ swl) * 8);

    for (int k0 = 0; k0 < 1024; k0 += 64) {
        __syncthreads();                            // prev tile consumed
        async16(gA + k0,             lA);
        async16(gA + k0 +  8 * 1024, lA + 512);
        async16(gA + k0 + 16 * 1024, lA + 1024);
        async16(gA + k0 + 24 * 1024, lA + 1536);
        async16(gB + k0,             lB);
        async16(gB + k0 +  8 * 1024, lB + 512);
        async16(gB + k0 + 16 * 1024, lB + 1024);
        async16(gB + k0 + 24 * 1024, lB + 1536);
        __syncthreads();                            // vmcnt(0) drain + barrier

        bf16x8 af[4][2], bf[4][2];
        for (int i = 0; i < 4; i++) {
            af[i][0] = *(const bf16x8*)(As + aB0 + i * 16 * 64);
            af[i][1] = *(const bf16x8*)(As + aB1 + i * 16 * 64);
        }
        for (int j = 0; j < 4; j++) {
            bf[j][0] = *(const bf16x8*)(Bs + bB0 + j * 16 * 64);
            bf[j][1] = *(const bf16x8*)(Bs + bB1 + j * 16 * 64);
        }
        for (int i = 0; i < 4; i++)
            for (int j = 0; j < 4; j++) {
                acc[i][j] = __builtin_amdgcn_mfma_f32_16x16x32_bf16(af[i][0], bf[j][0], acc[i][j], 0, 0, 0);
                acc[i][j] = __builtin_amdgcn_mfma_f32_16x16x32_bf16(af[i][1], bf[j][1], acc[i][j], 0, 0, 0);
            }
    }

    // epilogue: C[m][n], m = m0+wm+i*16+quad*4+r, n_col = n0+wn+j*16+l15
    const float QSC = 0.125f * 1.44269504f;        // folded scale*log2e for q
    for (int i = 0; i < 4; i++) {
        int gm   = m0 + wm + i * 16 + quad * 4;
        int b    = gm >> 11;                       // / 2048
        int nloc = gm & 2047;
        for (int j = 0; j < 4; j++) {
            int gn    = n0 + wn + j * 16 + l15;
            int which = gn >> 10;                  // 0=q 1=k 2=v (wave-uniform)
            int cc    = gn & 1023;
            int h     = cc >> 6;
            int d     = cc & 63;
            size_t bh = (size_t)(b * 16 + h);
            if (which == 2) {
                ushort4 w4;
                w4.x = f2b(acc[i][j][0]);
                w4.y = f2b(acc[i][j][1]);
                w4.z = f2b(acc[i][j][2]);
                w4.w = f2b(acc[i][j][3]);
                *(ushort4*)(vt + (bh * 64 + d) * 2048 + nloc) = w4;  // 4 consecutive n
            } else {
                u16* dst = (which == 0) ? q : k;
                float sc = (which == 0) ? QSC : 1.0f;
                for (int r = 0; r < 4; r++)
                    dst[(bh * 2048 + nloc + r) * 64 + d] = f2b(acc[i][j][r] * sc);
            }
        }
    }
}

// ---------------------------------------------------------------------------
// Kernel 4: flash attention — R11: restore 4 blocks/CU (kill the grid tail).
// R10 post-mortem: LDS 51200 B -> only 3 blocks/CU but grid = 4/CU -> 768+256
// two-phase dispatch; the 256-block tail runs at 4 waves/CU (latency-bound
// R7 regime).  Occupancy counter 25% (not 37.5%) confirms.  R9/R10's real
// wins (FETCH 140->42 MB, counted vmcnt) were eaten by the tail.
// Fix: LDS 51200 -> 37888 B (x4 = 148 KB <= 160 KB):
//   - ring-3 K/V buffers (depth-2 prefetch safe: stage(j+2)->buf (j-1)%3,
//     last read body j-1, published by barrier(j));
//   - Ms 8KB copy dropped; 128 B mask tile staged through the SAME async16
//     ring (3rd VMEM op/tile, vmcnt(3)); full-wave issue with (lane&7)
//     source clamp (lanes 8-63 write dup data into Msr pad, never read).
//   - tile loop unrolled x3 (64 = 21*3 + 1 tail) -> all buf indices static.
// Prologue drains qf/nmq global loads (vmcnt(0)) before ring staging so the
// in-loop vmcnt FIFO arithmetic stays exact.  Kept: XCD 1D grid, mask-as-
// C-init, ones-MFMA denominator, setprio.
// Falsifier: dur ~145 at occupancy ~37% -> steady-state wall -> pivot GEMM.
// ---------------------------------------------------------------------------
__global__ __launch_bounds__(256, 4) void attn_kernel(const u16* __restrict__ q,
                                                      const u16* __restrict__ k,
                                                      const u16* __restrict__ vt,
                                                      const float* __restrict__ mask,
                                                      float* __restrict__ out) {
    __shared__ u16 Ks[3][32 * 64];    // [key][d]  linear, source-swizzled (12 KB)
    __shared__ u16 Vs[3][64 * 32];    // [d][key]  linear, source-swizzled (12 KB)
    __shared__ u16 Ps[4][32 * 40];    // per-wave [q][key], stride 40 (10 KB)
    __shared__ __align__(16) float Msr[3][256];    // mask tile ring (3 KB; 32 real + pad)

    int tid  = threadIdx.x;
    int wave = tid >> 6, lane = tid & 63, l15 = lane & 15, quad = lane >> 4;
    int bid = blockIdx.x;             // 1D: bh fastest -> XCD = bh%8 cluster
    int bh = bid & 63, qb = bid >> 6;
    int b = bh >> 4, h = bh & 15;
    size_t base = (size_t)bh * (N_ * 64);
    int q0 = qb * 128 + wave * 32;
    const float* mkb = mask + b * N_;

    // Q as B-operand fragments (q pre-scaled by 0.125*log2e at GEMM time)
    bf16x8 qf[2][2];
#pragma unroll
    for (int s = 0; s < 2; s++)
#pragma unroll
        for (int dc = 0; dc < 2; dc++)
            qf[s][dc] = *(const bf16x8*)(q + base + (size_t)(q0 + s * 16 + l15) * 64 + dc * 32 + quad * 8);

    const float L2E = 1.44269504f;
    float nmq[2];
    nmq[0] = -L2E * mkb[q0 + l15];
    nmq[1] = -L2E * mkb[q0 + 16 + l15];

    // all-ones B-fragment for the denominator MFMA
    bf16x8 onef;
#pragma unroll
    for (int i = 0; i < 8; i++) onef[i] = (__bf16)1.0f;

    floatx4 acc[2][4];                // [s][dt] PV accumulator
    floatx4 accl[2];                  // [s]     row-sum accumulator (denominator)
#pragma unroll
    for (int s = 0; s < 2; s++) {
        accl[s] = floatx4{0.f, 0.f, 0.f, 0.f};
#pragma unroll
        for (int dt = 0; dt < 4; dt++)
            acc[s][dt] = floatx4{0.f, 0.f, 0.f, 0.f};
    }

    // async16 staging, 1 K + 1 V + 1 M instr per wave per tile:
    //   K: 8 rows x 8 chunks;  wave w covers K rows [w*8,  w*8+8)
    //   V: 16 rows x 4 chunks; wave w covers V rows [w*16, w*16+16)
    //   M: 128 B mask tile, all waves duplicate (lane&7 source clamp)
    int krow = wave * 8  + (lane >> 3);
    int kcol = ((lane & 7) ^ (lane >> 3)) * 8;            // chunk ^ (r&7)
    int vrow = wave * 16 + (lane >> 2);
    int vcol = ((lane & 3) ^ ((lane >> 2) & 3)) * 8;      // chunk ^ (r&3)
    const u16* gK = k  + base + (size_t)krow * 64 + kcol;            // += kt*64
    const u16* gV = vt + ((size_t)bh * 64 + vrow) * 2048 + vcol;     // += kt
    const float* gM = mkb + (lane & 7) * 4;                          // += kt
    int wof = wave * 512;             // wave-uniform LDS stage offset

    // loop-invariant swizzled frag-read offsets
    int a0 = ((quad    ) ^ (l15 & 7)) * 8;    // K chunks 0..7  -> d = quad*8
    int a1 = ((4 + quad) ^ (l15 & 7)) * 8;    //                -> d = 32+quad*8
    int av = ( quad      ^ (l15 & 3)) * 8;    // V chunks 0..3  -> key = quad*8

    u16* Pw = Ps[wave];

    // one KVBLK=32 tile body; barrier + counted vmcnt(3) at TOP.
    auto TILE = [&](int kt, const u16* Kb, const u16* Vb, const float* Mb,
                    u16* Kn, u16* Vn, float* Mn) {
        asm volatile("s_waitcnt vmcnt(3)" ::: "memory");
        __builtin_amdgcn_s_barrier();
        __builtin_amdgcn_sched_barrier(0);
        int nkt = kt + 64; if (nkt > N_ - 32) nkt = N_ - 32;   // clamp (dead restage)
        async16(gK + (size_t)nkt * 64, Kn);
        async16(gV + nkt,              Vn);
        async16p(gM + nkt,             Mn);
        float4 mkv0 = *(const float4*)(Mb + quad * 4);
        float4 mkv1 = *(const float4*)(Mb + 16 + quad * 4);
        // S^T (key x q): C seeded with nmq*mk (mask add for free); p = exp2(S)
#pragma unroll
        for (int t = 0; t < 2; t++) {
            bf16x8 kf0 = *(const bf16x8*)(Kb + (t * 16 + l15) * 64 + a0);
            bf16x8 kf1 = *(const bf16x8*)(Kb + (t * 16 + l15) * 64 + a1);
            float4 mk = t ? mkv1 : mkv0;
#pragma unroll
            for (int s = 0; s < 2; s++) {
                floatx4 sa;
                sa[0] = nmq[s] * mk.x;
                sa[1] = nmq[s] * mk.y;
                sa[2] = nmq[s] * mk.z;
                sa[3] = nmq[s] * mk.w;
                __builtin_amdgcn_s_setprio(1);
                sa = __builtin_amdgcn_mfma_f32_16x16x32_bf16(kf0, qf[s][0], sa, 0, 0, 0);
                sa = __builtin_amdgcn_mfma_f32_16x16x32_bf16(kf1, qf[s][1], sa, 0, 0, 0);
                __builtin_amdgcn_s_setprio(0);
                float p0 = exp2f(sa[0]);
                float p1 = exp2f(sa[1]);
                float p2 = exp2f(sa[2]);
                float p3 = exp2f(sa[3]);
                uint2 w; w.x = pk2(p0, p1); w.y = pk2(p2, p3);
                *(uint2*)(Pw + (s * 16 + l15) * 40 + t * 16 + quad * 4) = w;
            }
        }
        // PV (+ denominator via ones-MFMA): K-dim = 32 keys = 1 MFMA each
        bf16x8 pf0 = *(const bf16x8*)(Pw + l15 * 40 + quad * 8);
        bf16x8 pf1 = *(const bf16x8*)(Pw + (16 + l15) * 40 + quad * 8);
        __builtin_amdgcn_s_setprio(1);
        accl[0] = __builtin_amdgcn_mfma_f32_16x16x32_bf16(pf0, onef, accl[0], 0, 0, 0);
        accl[1] = __builtin_amdgcn_mfma_f32_16x16x32_bf16(pf1, onef, accl[1], 0, 0, 0);
        __builtin_amdgcn_s_setprio(0);
#pragma unroll
        for (int dt = 0; dt < 4; dt++) {
            bf16x8 vf = *(const bf16x8*)(Vb + (dt * 16 + l15) * 32 + av);
            __builtin_amdgcn_s_setprio(1);
            acc[0][dt] = __builtin_amdgcn_mfma_f32_16x16x32_bf16(pf0, vf, acc[0][dt], 0, 0, 0);
            acc[1][dt] = __builtin_amdgcn_mfma_f32_16x16x32_bf16(pf1, vf, acc[1][dt], 0, 0, 0);
            __builtin_amdgcn_s_setprio(0);
        }
    };

    // prologue: drain qf/nmq loads so the vmcnt FIFO is clean, then stage
    // tiles 0,1 (3 ops each) and full-drain once.
    asm volatile("s_waitcnt vmcnt(0)" ::: "memory");
    async16(gK,            Ks[0] + wof);
    async16(gV,            Vs[0] + wof);
    async16p(gM,           Msr[0]);
    async16(gK + 32 * 64,  Ks[1] + wof);
    async16(gV + 32,       Vs[1] + wof);
    async16p(gM + 32,      Msr[1]);
    __syncthreads();

    // 64 tiles: 21 x 3 (ring-3, static buffers) + 1 tail
    for (int m = 0; m < 21; ++m) {
        int kt = m * 96;
        TILE(kt,      Ks[0], Vs[0], Msr[0], Ks[2] + wof, Vs[2] + wof, Msr[2]);
        TILE(kt + 32, Ks[1], Vs[1], Msr[1], Ks[0] + wof, Vs[0] + wof, Msr[0]);
        TILE(kt + 64, Ks[2], Vs[2], Msr[2], Ks[1] + wof, Vs[1] + wof, Msr[1]);
    }
    TILE(2016, Ks[0], Vs[0], Msr[0], Ks[2] + wof, Vs[2] + wof, Msr[2]);  // tile 63

    // epilogue: accl[s][r] = l(q = s*16+quad*4+r) — per-lane, no shuffles.
    // acc C-layout: col=l15=d, row=quad*4+r=q (same row-map as accl).
#pragma unroll
    for (int s = 0; s < 2; s++) {
#pragma unroll
        for (int r = 0; r < 4; r++) {
            float ir = 1.0f / accl[s][r];
            int qrow = q0 + s * 16 + quad * 4 + r;
            float* orow = out + ((size_t)(b * N_ + qrow)) * C_ + h * 64;
#pragma unroll
            for (int dt = 0; dt < 4; dt++)
                orow[dt * 16 + l15] = acc[s][dt][r] * ir;
        }
    }
}

// ---------------------------------------------------------------------------
extern "C" void kernel_launch(void* const* d_in, const int* in_sizes, int n_in,
                              void* d_out, int out_size, void* d_ws, size_t ws_size,
                              hipStream_t stream) {
    const float* inp  = (const float*)d_in[0];   // inputs  [B,N,C] fp32
    const float* mask = (const float*)d_in[1];   // mask    [B,N]   fp32
    const float* W    = (const float*)d_in[2];   // W_qkv   [C,3C]  fp32
    float* out = (float*)d_out;                  // [B,N,C] fp32

    char* ws = (char*)d_ws;
    u16* x  = (u16*)ws;                              // 16 MB  x=in+PE bf16
    u16* Wt = (u16*)(ws + 16777216);                 // 6 MB   W^T bf16
    u16* q  = (u16*)(ws + 23068672);                 // [B,H,N,64] bf16 (pre-scaled)
    u16* k  = q + 8388608;
    u16* vt = k + 8388608;                           // [B,H,64,N] bf16 (v transposed)

    pe_add_kernel<<<16384, 256, 0, stream>>>(inp, x);
    wt_kernel<<<dim3(96, 32), 256, 0, stream>>>(W, Wt);
    qkv_gemm_kernel<<<dim3(64, 24), 256, 0, stream>>>(x, Wt, q, k, vt);
    attn_kernel<<<1024, 256, 0, stream>>>(q, k, vt, mask, out);
}

// Round 12
// 242.813 us; speedup vs baseline: 1.1626x; 1.1119x over previous
//
#include <hip/hip_runtime.h>
#include <hip/hip_bf16.h>

typedef unsigned short u16;
typedef __bf16 bf16x8 __attribute__((ext_vector_type(8)));
typedef float floatx4 __attribute__((ext_vector_type(4)));

#define B_ 4
#define N_ 2048
#define C_ 1024
#define H_ 16
#define HD_ 64

__device__ __forceinline__ float b2f(u16 u) {
    union { float f; unsigned int i; } v; v.i = ((unsigned int)u) << 16; return v.f;
}
__device__ __forceinline__ u16 f2b(float f) {
    union { float f; unsigned int i; } v; v.f = f;
    unsigned int i = v.i;
    unsigned int r = i + 0x7FFFu + ((i >> 16) & 1u);
    return (u16)(r >> 16);
}
__device__ __forceinline__ unsigned int pk2(float a, float b) {
    __hip_bfloat162 t = __float22bfloat162_rn(float2{a, b});
    unsigned int u; __builtin_memcpy(&u, &t, 4); return u;
}
// hardware exp2 via BUILTIN (not inline asm): lowers to v_exp_f32 AND lets
// the backend insert the gfx950 trans-use wait state.  R12's inline-asm
// version hid the producer opcode from the hazard recognizer -> consumer
// read the register before the trans pipe wrote it -> absmax 131 garbage.
__device__ __forceinline__ float fexp2(float x) {
    return __builtin_amdgcn_exp2f(x);
}
// async global->LDS, 16B per lane; LDS dest = wave-uniform base + lane*16
__device__ __forceinline__ void async16(const u16* g, u16* l) {
    __builtin_amdgcn_global_load_lds((const __attribute__((address_space(1))) unsigned int*)g,
                                     (__attribute__((address_space(3))) unsigned int*)l,
                                     16, 0, 0);
}
__device__ __forceinline__ void async16p(const void* g, void* l) {
    __builtin_amdgcn_global_load_lds((const __attribute__((address_space(1))) unsigned int*)g,
                                     (__attribute__((address_space(3))) unsigned int*)l,
                                     16, 0, 0);
}

// ---------------------------------------------------------------------------
// Kernel 1: x = inputs(fp32) + sinusoidal PE  ->  bf16 x.
// ---------------------------------------------------------------------------
__global__ __launch_bounds__(256) void pe_add_kernel(const float* __restrict__ in,
                                                     u16* __restrict__ x) {
    int idx = blockIdx.x * 256 + threadIdx.x;      // pair index, total B*N*C/2
    int cp  = idx & 511;                            // C/2 = 512 pairs per row
    int row = idx >> 9;                             // b*N + n
    int n   = row & (N_ - 1);
    float r = exp2f(-13.287712379549449f * ((float)cp * (1.0f / 512.0f)));
    float ang = (float)n * r;
    float s, c;
    sincosf(ang, &s, &c);
    float2 pr = ((const float2*)in)[idx];
    unsigned int o = ((unsigned int)f2b(pr.y + c) << 16) | (unsigned int)f2b(pr.x + s);
    ((unsigned int*)x)[idx] = o;
}

// ---------------------------------------------------------------------------
// Kernel 2: transpose W_qkv fp32 [1024][3072] -> bf16 Wt [3072][1024].
// ---------------------------------------------------------------------------
__global__ __launch_bounds__(256) void wt_kernel(const float* __restrict__ W,
                                                 u16* __restrict__ Wt) {
    __shared__ u16 tile[32][33];
    int bx = blockIdx.x;            // over 3072/32 = 96
    int by = blockIdx.y;            // over 1024/32 = 32
    int tx = threadIdx.x & 31;
    int ty = threadIdx.x >> 5;      // 0..7
    for (int i = 0; i < 32; i += 8)
        tile[ty + i][tx] = f2b(W[(size_t)(by * 32 + ty + i) * 3072 + bx * 32 + tx]);
    __syncthreads();
    for (int i = 0; i < 32; i += 8)
        Wt[(size_t)(bx * 32 + ty + i) * 1024 + by * 32 + tx] = tile[tx][ty + i];
}

// ---------------------------------------------------------------------------
// Kernel 3: QKV GEMM, BK=64 (unchanged, proven).
// ---------------------------------------------------------------------------
__global__ __launch_bounds__(256) void qkv_gemm_kernel(const u16* __restrict__ X,
                                                       const u16* __restrict__ Wt,
                                                       u16* __restrict__ q,
                                                       u16* __restrict__ k,
                                                       u16* __restrict__ vt) {
    __shared__ u16 As[128 * 64];
    __shared__ u16 Bs[128 * 64];
    int tid  = threadIdx.x;
    int wave = tid >> 6, lane = tid & 63, l15 = lane & 15, quad = lane >> 4;
    int m0 = blockIdx.x * 128;
    int n0 = blockIdx.y * 128;
    int wm = (wave & 1) * 64;
    int wn = (wave >> 1) * 64;

    floatx4 acc[4][4];
    for (int i = 0; i < 4; i++)
        for (int j = 0; j < 4; j++)
            acc[i][j] = floatx4{0.f, 0.f, 0.f, 0.f};

    // staging: wave stages rows [wave*32, wave*32+32), 4 instrs of 8 rows each.
    // LDS[r][c'] = global[r][c' ^ (r&7)]  (c' = lane&7, r&7 = lane>>3)
    int rowOff = wave * 32 + (lane >> 3);
    int colSw  = ((lane & 7) ^ (lane >> 3)) * 8;
    const u16* gA = X  + (size_t)(m0 + rowOff) * 1024 + colSw;
    const u16* gB = Wt + (size_t)(n0 + rowOff) * 1024 + colSw;
    u16* lA = As + wave * 2048;                    // 32 rows * 64 elems
    u16* lB = Bs + wave * 2048;

    // loop-invariant frag read offsets: chunk g=kh*4+quad stored at g^(l15&7)
    int swl = l15 & 7;
    int aB0 = (wm + l15) * 64 + ((quad ^ swl) * 8);
    int aB1 = (wm + l15) * 64 + (((4 + quad) ^ swl) * 8);
    int bB0 = (wn + l15) * 64 + ((quad ^ swl) * 8);
    int bB1 = (wn + l15) * 64 + (((4 + quad) ^ swl) * 8);

    for (int k0 = 0; k0 < 1024; k0 += 64) {
        __syncthreads();                            // prev tile consumed
        async16(gA + k0,             lA);
        async16(gA + k0 +  8 * 1024, lA + 512);
        async16(gA + k0 + 16 * 1024, lA + 1024);
        async16(gA + k0 + 24 * 1024, lA + 1536);
        async16(gB + k0,             lB);
        async16(gB + k0 +  8 * 1024, lB + 512);
        async16(gB + k0 + 16 * 1024, lB + 1024);
        async16(gB + k0 + 24 * 1024, lB + 1536);
        __syncthreads();                            // vmcnt(0) drain + barrier

        bf16x8 af[4][2], bf[4][2];
        for (int i = 0; i < 4; i++) {
            af[i][0] = *(const bf16x8*)(As + aB0 + i * 16 * 64);
            af[i][1] = *(const bf16x8*)(As + aB1 + i * 16 * 64);
        }
        for (int j = 0; j < 4; j++) {
            bf[j][0] = *(const bf16x8*)(Bs + bB0 + j * 16 * 64);
            bf[j][1] = *(const bf16x8*)(Bs + bB1 + j * 16 * 64);
        }
        for (int i = 0; i < 4; i++)
            for (int j = 0; j < 4; j++) {
                acc[i][j] = __builtin_amdgcn_mfma_f32_16x16x32_bf16(af[i][0], bf[j][0], acc[i][j], 0, 0, 0);
                acc[i][j] = __builtin_amdgcn_mfma_f32_16x16x32_bf16(af[i][1], bf[j][1], acc[i][j], 0, 0, 0);
            }
    }

    // epilogue: C[m][n], m = m0+wm+i*16+quad*4+r, n_col = n0+wn+j*16+l15
    const float QSC = 0.125f * 1.44269504f;        // folded scale*log2e for q
    for (int i = 0; i < 4; i++) {
        int gm   = m0 + wm + i * 16 + quad * 4;
        int b    = gm >> 11;                       // / 2048
        int nloc = gm & 2047;
        for (int j = 0; j < 4; j++) {
            int gn    = n0 + wn + j * 16 + l15;
            int which = gn >> 10;                  // 0=q 1=k 2=v (wave-uniform)
            int cc    = gn & 1023;
            int h     = cc >> 6;
            int d     = cc & 63;
            size_t bh = (size_t)(b * 16 + h);
            if (which == 2) {
                ushort4 w4;
                w4.x = f2b(acc[i][j][0]);
                w4.y = f2b(acc[i][j][1]);
                w4.z = f2b(acc[i][j][2]);
                w4.w = f2b(acc[i][j][3]);
                *(ushort4*)(vt + (bh * 64 + d) * 2048 + nloc) = w4;  // 4 consecutive n
            } else {
                u16* dst = (which == 0) ? q : k;
                float sc = (which == 0) ? QSC : 1.0f;
                for (int r = 0; r < 4; r++)
                    dst[(bh * 2048 + nloc + r) * 64 + d] = f2b(acc[i][j][r] * sc);
            }
        }
    }
}

// ---------------------------------------------------------------------------
// Kernel 4: flash attention — R13: R12's exp2 diet via BUILTIN (hazard-safe).
// R12 post-mortem: inline-asm v_exp_f32 hid the trans-op from the hazard
// recognizer -> no wait state before the consumer -> garbage (absmax 131).
// Fix: __builtin_amdgcn_exp2f (same 1 instr, backend inserts the s_nop).
// cvt_pk reverted to the proven pk2 sequence this round (one variable).
// Structure (ring-3, vmcnt(3), XCD grid, mask-as-C-init, ones-MFMA denom,
// setprio) = R11, which passed at absmax 0.0078.
// Falsifier: VALUBusy drops >=10pts but dur <5us better -> VALU not binding
// -> pivot to V-path bank conflicts / GEMM.
// ---------------------------------------------------------------------------
__global__ __launch_bounds__(256, 4) void attn_kernel(const u16* __restrict__ q,
                                                      const u16* __restrict__ k,
                                                      const u16* __restrict__ vt,
                                                      const float* __restrict__ mask,
                                                      float* __restrict__ out) {
    __shared__ u16 Ks[3][32 * 64];    // [key][d]  linear, source-swizzled (12 KB)
    __shared__ u16 Vs[3][64 * 32];    // [d][key]  linear, source-swizzled (12 KB)
    __shared__ u16 Ps[4][32 * 40];    // per-wave [q][key], stride 40 (10 KB)
    __shared__ __align__(16) float Msr[3][256];    // mask tile ring (3 KB; 32 real + pad)

    int tid  = threadIdx.x;
    int wave = tid >> 6, lane = tid & 63, l15 = lane & 15, quad = lane >> 4;
    int bid = blockIdx.x;             // 1D: bh fastest -> XCD = bh%8 cluster
    int bh = bid & 63, qb = bid >> 6;
    int b = bh >> 4, h = bh & 15;
    size_t base = (size_t)bh * (N_ * 64);
    int q0 = qb * 128 + wave * 32;
    const float* mkb = mask + b * N_;

    // Q as B-operand fragments (q pre-scaled by 0.125*log2e at GEMM time)
    bf16x8 qf[2][2];
#pragma unroll
    for (int s = 0; s < 2; s++)
#pragma unroll
        for (int dc = 0; dc < 2; dc++)
            qf[s][dc] = *(const bf16x8*)(q + base + (size_t)(q0 + s * 16 + l15) * 64 + dc * 32 + quad * 8);

    const float L2E = 1.44269504f;
    float nmq[2];
    nmq[0] = -L2E * mkb[q0 + l15];
    nmq[1] = -L2E * mkb[q0 + 16 + l15];

    // all-ones B-fragment for the denominator MFMA
    bf16x8 onef;
#pragma unroll
    for (int i = 0; i < 8; i++) onef[i] = (__bf16)1.0f;

    floatx4 acc[2][4];                // [s][dt] PV accumulator
    floatx4 accl[2];                  // [s]     row-sum accumulator (denominator)
#pragma unroll
    for (int s = 0; s < 2; s++) {
        accl[s] = floatx4{0.f, 0.f, 0.f, 0.f};
#pragma unroll
        for (int dt = 0; dt < 4; dt++)
            acc[s][dt] = floatx4{0.f, 0.f, 0.f, 0.f};
    }

    // async16 staging, 1 K + 1 V + 1 M instr per wave per tile:
    //   K: 8 rows x 8 chunks;  wave w covers K rows [w*8,  w*8+8)
    //   V: 16 rows x 4 chunks; wave w covers V rows [w*16, w*16+16)
    //   M: 128 B mask tile, all waves duplicate (lane&7 source clamp)
    int krow = wave * 8  + (lane >> 3);
    int kcol = ((lane & 7) ^ (lane >> 3)) * 8;            // chunk ^ (r&7)
    int vrow = wave * 16 + (lane >> 2);
    int vcol = ((lane & 3) ^ ((lane >> 2) & 3)) * 8;      // chunk ^ (r&3)
    const u16* gK = k  + base + (size_t)krow * 64 + kcol;            // += kt*64
    const u16* gV = vt + ((size_t)bh * 64 + vrow) * 2048 + vcol;     // += kt
    const float* gM = mkb + (lane & 7) * 4;                          // += kt
    int wof = wave * 512;             // wave-uniform LDS stage offset

    // loop-invariant swizzled frag-read offsets
    int a0 = ((quad    ) ^ (l15 & 7)) * 8;    // K chunks 0..7  -> d = quad*8
    int a1 = ((4 + quad) ^ (l15 & 7)) * 8;    //                -> d = 32+quad*8
    int av = ( quad      ^ (l15 & 3)) * 8;    // V chunks 0..3  -> key = quad*8

    u16* Pw = Ps[wave];

    // one KVBLK=32 tile body; barrier + counted vmcnt(3) at TOP.
    auto TILE = [&](int kt, const u16* Kb, const u16* Vb, const float* Mb,
                    u16* Kn, u16* Vn, float* Mn) {
        asm volatile("s_waitcnt vmcnt(3)" ::: "memory");
        __builtin_amdgcn_s_barrier();
        __builtin_amdgcn_sched_barrier(0);
        int nkt = kt + 64; if (nkt > N_ - 32) nkt = N_ - 32;   // clamp (dead restage)
        async16(gK + (size_t)nkt * 64, Kn);
        async16(gV + nkt,              Vn);
        async16p(gM + nkt,             Mn);
        float4 mkv0 = *(const float4*)(Mb + quad * 4);
        float4 mkv1 = *(const float4*)(Mb + 16 + quad * 4);
        // S^T (key x q): C seeded with nmq*mk (mask add for free); p = exp2(S)
#pragma unroll
        for (int t = 0; t < 2; t++) {
            bf16x8 kf0 = *(const bf16x8*)(Kb + (t * 16 + l15) * 64 + a0);
            bf16x8 kf1 = *(const bf16x8*)(Kb + (t * 16 + l15) * 64 + a1);
            float4 mk = t ? mkv1 : mkv0;
#pragma unroll
            for (int s = 0; s < 2; s++) {
                floatx4 sa;
                sa[0] = nmq[s] * mk.x;
                sa[1] = nmq[s] * mk.y;
                sa[2] = nmq[s] * mk.z;
                sa[3] = nmq[s] * mk.w;
                __builtin_amdgcn_s_setprio(1);
                sa = __builtin_amdgcn_mfma_f32_16x16x32_bf16(kf0, qf[s][0], sa, 0, 0, 0);
                sa = __builtin_amdgcn_mfma_f32_16x16x32_bf16(kf1, qf[s][1], sa, 0, 0, 0);
                __builtin_amdgcn_s_setprio(0);
                float p0 = fexp2(sa[0]);
                float p1 = fexp2(sa[1]);
                float p2 = fexp2(sa[2]);
                float p3 = fexp2(sa[3]);
                uint2 w; w.x = pk2(p0, p1); w.y = pk2(p2, p3);
                *(uint2*)(Pw + (s * 16 + l15) * 40 + t * 16 + quad * 4) = w;
            }
        }
        // PV (+ denominator via ones-MFMA): K-dim = 32 keys = 1 MFMA each
        bf16x8 pf0 = *(const bf16x8*)(Pw + l15 * 40 + quad * 8);
        bf16x8 pf1 = *(const bf16x8*)(Pw + (16 + l15) * 40 + quad * 8);
        __builtin_amdgcn_s_setprio(1);
        accl[0] = __builtin_amdgcn_mfma_f32_16x16x32_bf16(pf0, onef, accl[0], 0, 0, 0);
        accl[1] = __builtin_amdgcn_mfma_f32_16x16x32_bf16(pf1, onef, accl[1], 0, 0, 0);
        __builtin_amdgcn_s_setprio(0);
#pragma unroll
        for (int dt = 0; dt < 4; dt++) {
            bf16x8 vf = *(const bf16x8*)(Vb + (dt * 16 + l15) * 32 + av);
            __builtin_amdgcn_s_setprio(1);
            acc[0][dt] = __builtin_amdgcn_mfma_f32_16x16x32_bf16(pf0, vf, acc[0][dt], 0, 0, 0);
            acc[1][dt] = __builtin_amdgcn_mfma_f32_16x16x32_bf16(pf1, vf, acc[1][dt], 0, 0, 0);
            __builtin_amdgcn_s_setprio(0);
        }
    };

    // prologue: drain qf/nmq loads so the vmcnt FIFO is clean, then stage
    // tiles 0,1 (3 ops each) and full-drain once.
    asm volatile("s_waitcnt vmcnt(0)" ::: "memory");
    async16(gK,            Ks[0] + wof);
    async16(gV,            Vs[0] + wof);
    async16p(gM,           Msr[0]);
    async16(gK + 32 * 64,  Ks[1] + wof);
    async16(gV + 32,       Vs[1] + wof);
    async16p(gM + 32,      Msr[1]);
    __syncthreads();

    // 64 tiles: 21 x 3 (ring-3, static buffers) + 1 tail
    for (int m = 0; m < 21; ++m) {
        int kt = m * 96;
        TILE(kt,      Ks[0], Vs[0], Msr[0], Ks[2] + wof, Vs[2] + wof, Msr[2]);
        TILE(kt + 32, Ks[1], Vs[1], Msr[1], Ks[0] + wof, Vs[0] + wof, Msr[0]);
        TILE(kt + 64, Ks[2], Vs[2], Msr[2], Ks[1] + wof, Vs[1] + wof, Msr[1]);
    }
    TILE(2016, Ks[0], Vs[0], Msr[0], Ks[2] + wof, Vs[2] + wof, Msr[2]);  // tile 63

    // epilogue: accl[s][r] = l(q = s*16+quad*4+r) — per-lane, no shuffles.
    // acc C-layout: col=l15=d, row=quad*4+r=q (same row-map as accl).
#pragma unroll
    for (int s = 0; s < 2; s++) {
#pragma unroll
        for (int r = 0; r < 4; r++) {
            float ir = 1.0f / accl[s][r];
            int qrow = q0 + s * 16 + quad * 4 + r;
            float* orow = out + ((size_t)(b * N_ + qrow)) * C_ + h * 64;
#pragma unroll
            for (int dt = 0; dt < 4; dt++)
                orow[dt * 16 + l15] = acc[s][dt][r] * ir;
        }
    }
}

// ---------------------------------------------------------------------------
extern "C" void kernel_launch(void* const* d_in, const int* in_sizes, int n_in,
                              void* d_out, int out_size, void* d_ws, size_t ws_size,
                              hipStream_t stream) {
    const float* inp  = (const float*)d_in[0];   // inputs  [B,N,C] fp32
    const float* mask = (const float*)d_in[1];   // mask    [B,N]   fp32
    const float* W    = (const float*)d_in[2];   // W_qkv   [C,3C]  fp32
    float* out = (float*)d_out;                  // [B,N,C] fp32

    char* ws = (char*)d_ws;
    u16* x  = (u16*)ws;                              // 16 MB  x=in+PE bf16
    u16* Wt = (u16*)(ws + 16777216);                 // 6 MB   W^T bf16
    u16* q  = (u16*)(ws + 23068672);                 // [B,H,N,64] bf16 (pre-scaled)
    u16* k  = q + 8388608;
    u16* vt = k + 8388608;                           // [B,H,64,N] bf16 (v transposed)

    pe_add_kernel<<<16384, 256, 0, stream>>>(inp, x);
    wt_kernel<<<dim3(96, 32), 256, 0, stream>>>(W, Wt);
    qkv_gemm_kernel<<<dim3(64, 24), 256, 0, stream>>>(x, Wt, q, k, vt);
    attn_kernel<<<1024, 256, 0, stream>>>(q, k, vt, mask, out);
}